// Round 4
// baseline (168.200 us; speedup 1.0000x reference)
//
#include <hip/hip_runtime.h>

// Problem: B=65536, C=2, P=41, L=4 cross-entropy + boundary weights + connectivity
// loss = mean( ce * w + 0.001 * connectivity )
//   ce  = relu(l_other - l_target) + log1p(exp(-|l1-l0|))     (C=2 log-softmax)
//   w   = 1 + |t[p]-t[p+-1]| + 0.5|t[p]-t[p+-2]|  (bounds-guarded; targets in {0,1} -> XOR)
//   conn= pred[p] != pred[p-1], pred = (l1 > l0)   (argmax first-max tie rule)
constexpr int B   = 65536;
constexpr int P   = 41;
constexpr int CPL4 = 82;                  // float4 per batch of logits (2*41)
constexpr int NTH  = B * P;               // 2,686,976 (b,p) pairs
constexpr int GS   = 41 * 16384;          // grid stride = 671,744 (p invariant!)
constexpr int ITER = 4;                   // NTH / GS
constexpr int NBLK = GS / 256;            // 2624 blocks
constexpr float INV_N = 1.0f / (float)(B * P * 4);
constexpr float CW    = 0.001f;

__device__ __forceinline__ int pack_tgt(int4 v) {
    return (v.x & 1) | ((v.y & 1) << 1) | ((v.z & 1) << 2) | ((v.w & 1) << 3);
}
__device__ __forceinline__ int pack_pred(float4 c0, float4 c1) {
    return (c1.x > c0.x ? 1 : 0) | (c1.y > c0.y ? 2 : 0) |
           (c1.z > c0.z ? 4 : 0) | (c1.w > c0.w ? 8 : 0);
}

__global__ __launch_bounds__(256)
void lace_partial_kernel(const float4* __restrict__ lg4,
                         const int4*   __restrict__ tg4,
                         float*        __restrict__ partial)
{
    const int tid  = blockIdx.x * 256 + threadIdx.x;   // < GS, all active
    const int lane = threadIdx.x & 63;

    // p is invariant across grid-stride iterations (GS = 41*16384)
    int b = tid / P;              // magic-mul, once
    const int p = tid - b * P;

    const bool hm1 = (p >= 1), hp1 = (p <= P - 2);
    const bool hm2 = (p >= 2), hp2 = (p <= P - 3);
    const bool im1 = (lane >= 1), ip1 = (lane <= 62);
    const bool im2 = (lane >= 2), ip2 = (lane <= 61);

    float sum = 0.0f;
    int t = tid;

    #pragma unroll
    for (int k = 0; k < ITER; ++k) {
        const int f4 = b * CPL4 + p;
        float4 a0 = lg4[f4];          // logits[b,0,p,:]
        float4 a1 = lg4[f4 + P];      // logits[b,1,p,:]
        int4   tc = tg4[t];           // targets[b,p,:]

        int tp = pack_tgt(tc);        // 4 target bits
        int pp = pack_pred(a0, a1);   // 4 pred bits

        // neighbor packs via cross-lane (lane +-1/+-2 hold p +-1/+-2 of same b)
        int tm1 = __shfl_up  (tp, 1, 64);
        int tP1 = __shfl_down(tp, 1, 64);
        int tm2 = __shfl_up  (tp, 2, 64);
        int tP2 = __shfl_down(tp, 2, 64);
        int pm  = __shfl_up  (pp, 1, 64);

        // wave-edge fallbacks (rare: ~4 lanes/wave, guarded loads hit L1/L2)
        if (hm1 && !im1) {
            tm1 = pack_tgt(tg4[t - 1]);
            pm  = pack_pred(lg4[f4 - 1], lg4[f4 + P - 1]);
        }
        if (hp1 && !ip1) tP1 = pack_tgt(tg4[t + 1]);
        if (hm2 && !im2) tm2 = pack_tgt(tg4[t - 2]);
        if (hp2 && !ip2) tP2 = pack_tgt(tg4[t + 2]);

        // boundary-weight XOR masks (|ti - tj| = ti ^ tj for {0,1})
        const int xm1 = hm1 ? (tp ^ tm1) & 0xF : 0;
        const int xp1 = hp1 ? (tp ^ tP1) & 0xF : 0;
        const int xm2 = hm2 ? (tp ^ tm2) & 0xF : 0;
        const int xp2 = hp2 ? (tp ^ tP2) & 0xF : 0;

        const float* A0 = (const float*)&a0;
        const float* A1 = (const float*)&a1;

        #pragma unroll
        for (int l = 0; l < 4; ++l) {
            float d  = A1[l] - A0[l];                 // l1 - l0
            float ad = fabsf(d);
            float g  = __logf(1.0f + __expf(-ad));    // target-independent part
            float sd = ((tp >> l) & 1) ? -d : d;      // l_other - l_target
            float ce = fmaxf(sd, 0.0f) + g;

            float w = 1.0f
                    + (float)(((xm1 >> l) & 1) + ((xp1 >> l) & 1))
                    + 0.5f * (float)(((xm2 >> l) & 1) + ((xp2 >> l) & 1));
            sum += ce * w;
        }

        // connectivity for all 4 lanes at once
        if (hm1) sum += CW * (float)__popc((pp ^ pm) & 0xF);

        t += GS;
        b += 16384;
    }

    // wave(64) shuffle reduction -> LDS across 4 waves -> one store per block
    #pragma unroll
    for (int off = 32; off > 0; off >>= 1)
        sum += __shfl_down(sum, off, 64);

    __shared__ float wsum[4];
    int wid = threadIdx.x >> 6;
    if (lane == 0) wsum[wid] = sum;
    __syncthreads();
    if (threadIdx.x == 0)
        partial[blockIdx.x] = wsum[0] + wsum[1] + wsum[2] + wsum[3];
}

__global__ __launch_bounds__(1024)
void lace_reduce_kernel(const float* __restrict__ partial,
                        float*       __restrict__ out)
{
    float s = 0.0f;
    for (int i = threadIdx.x; i < NBLK; i += 1024)
        s += partial[i];

    #pragma unroll
    for (int off = 32; off > 0; off >>= 1)
        s += __shfl_down(s, off, 64);

    __shared__ float wsum[16];
    int lane = threadIdx.x & 63;
    int wid  = threadIdx.x >> 6;
    if (lane == 0) wsum[wid] = s;
    __syncthreads();
    if (threadIdx.x == 0) {
        float total = 0.0f;
        #pragma unroll
        for (int i = 0; i < 16; ++i) total += wsum[i];
        out[0] = total * INV_N;
    }
}

extern "C" void kernel_launch(void* const* d_in, const int* in_sizes, int n_in,
                              void* d_out, int out_size, void* d_ws, size_t ws_size,
                              hipStream_t stream) {
    const float4* lg4 = (const float4*)d_in[0];
    const int4*   tg4 = (const int4*)d_in[1];
    float* out     = (float*)d_out;
    float* partial = (float*)d_ws;   // 2624 floats

    lace_partial_kernel<<<NBLK, 256, 0, stream>>>(lg4, tg4, partial);
    lace_reduce_kernel<<<1, 1024, 0, stream>>>(partial, out);
}

// Round 5
// 160.877 us; speedup vs baseline: 1.0455x; 1.0455x over previous
//
#include <hip/hip_runtime.h>

// Problem: B=65536, C=2, P=41, L=4 cross-entropy + boundary weights + connectivity
// loss = mean( ce * w + 0.001 * conn )
//   ce  = relu(l_other - l_target) + log(1+exp(-|l1-l0|))   (C=2 log-softmax)
//   w   = 1 + |t[p]-t[p+-1]| + 0.5|t[p]-t[p+-2]|  (bounds-guarded; t in {0,1} -> XOR)
//   conn= pred[p] != pred[p-1], pred = (l1 > l0)
//
// Thread <-> (b, quad q): 4 consecutive p per thread. Neighbors p+-1/+-2 are
// in-register within the quad; only the quad rim needs extra (L1-hit) loads.
constexpr int B    = 65536;
constexpr int P    = 41;
constexpr int NQ   = 11;                 // ceil(41/4) quads per batch
constexpr int NTHR = B * NQ;             // 720,896 threads
constexpr int NBLK = NTHR / 256;         // 2,816 blocks
constexpr float INV_N = 1.0f / (float)(B * P * 4);
constexpr float CW    = 0.001f;

__device__ __forceinline__ int pack_tgt(int4 v) {
    return (v.x & 1) | ((v.y & 1) << 1) | ((v.z & 1) << 2) | ((v.w & 1) << 3);
}
__device__ __forceinline__ int pack_pred(float4 c0, float4 c1) {
    return (c1.x > c0.x ? 1 : 0) | (c1.y > c0.y ? 2 : 0) |
           (c1.z > c0.z ? 4 : 0) | (c1.w > c0.w ? 8 : 0);
}

__global__ __launch_bounds__(256)
void lace_partial_kernel(const float4* __restrict__ lg4,
                         const int4*   __restrict__ tg4,
                         float*        __restrict__ partial)
{
    const int tid = blockIdx.x * 256 + threadIdx.x;
    const int b   = tid / NQ;            // magic-mul
    const int q   = tid - b * NQ;
    const int p0  = q * 4;

    const int lbase = b * 82 + p0;       // float4 idx of logits[b,0,p0,:]
    const int tbase = b * 41 + p0;       // int4 idx of targets[b,p0,:]

    // ---- own loads: 8 float4 + 4 int4, contiguous 64B/lane chunks ----
    // tail quad (q==10, p0=40): clamp j to stay in the c=0 row / batch
    float4 c0v[4], c1v[4];
    int4   tv[4];
    #pragma unroll
    for (int j = 0; j < 4; ++j) {
        const int cl = (p0 + j <= 40) ? j : 0;   // clamp (only q==10)
        c0v[j] = lg4[lbase + cl];
        c1v[j] = lg4[lbase + 41 + cl];
        tv[j]  = tg4[tbase + cl];
    }

    // ---- rim neighbors (guarded, L1/L2-hit) ----
    int tm1b = 0, tm2b = 0, tp1b = 0, tp2b = 0, pmb = 0;
    if (p0 >= 1) {                       // q>=1 => p0>=4 => p0-2 also valid
        tm1b = pack_tgt(tg4[tbase - 1]);
        tm2b = pack_tgt(tg4[tbase - 2]);
        pmb  = pack_pred(lg4[lbase - 1], lg4[lbase + 40]);
    }
    if (p0 + 4 <= 40) tp1b = pack_tgt(tg4[tbase + 4]);
    if (p0 + 5 <= 40) tp2b = pack_tgt(tg4[tbase + 5]);

    // ---- pack own targets / preds to 4-bit masks ----
    int tb[4], pb[4];
    #pragma unroll
    for (int j = 0; j < 4; ++j) {
        tb[j] = pack_tgt(tv[j]);
        pb[j] = pack_pred(c0v[j], c1v[j]);
    }

    // ---- compute 4 (or 1, tail) pairs ----
    float sum = 0.0f;
    #pragma unroll
    for (int j = 0; j < 4; ++j) {
        if (j == 0 || p0 + j <= 40) {    // tail quad masks j>=1
            const int p  = p0 + j;
            const int tp = tb[j];
            const int prev1 = (j >= 1) ? tb[j-1] : tm1b;
            const int prev2 = (j >= 2) ? tb[j-2] : ((j == 1) ? tm1b : tm2b);
            const int next1 = (j <= 2) ? tb[j+1] : tp1b;
            const int next2 = (j <= 1) ? tb[j+2] : ((j == 2) ? tp1b : tp2b);
            const int prevp = (j >= 1) ? pb[j-1] : pmb;

            const int xm1 = (p >= 1)  ? (tp ^ prev1) & 0xF : 0;
            const int xm2 = (p >= 2)  ? (tp ^ prev2) & 0xF : 0;
            const int xp1 = (p <= 39) ? (tp ^ next1) & 0xF : 0;
            const int xp2 = (p <= 38) ? (tp ^ next2) & 0xF : 0;

            const float* A0 = (const float*)&c0v[j];
            const float* A1 = (const float*)&c1v[j];
            #pragma unroll
            for (int l = 0; l < 4; ++l) {
                float d  = A1[l] - A0[l];                 // l1 - l0
                float g  = __logf(1.0f + __expf(-fabsf(d)));
                float sd = ((tp >> l) & 1) ? -d : d;      // l_other - l_target
                float ce = fmaxf(sd, 0.0f) + g;
                float w  = 1.0f
                         + (float)(((xm1 >> l) & 1) + ((xp1 >> l) & 1))
                         + 0.5f * (float)(((xm2 >> l) & 1) + ((xp2 >> l) & 1));
                sum += ce * w;
            }
            if (p >= 1)
                sum += CW * (float)__popc((pb[j] ^ prevp) & 0xF);
        }
    }

    // ---- block reduction -> one partial per block ----
    #pragma unroll
    for (int off = 32; off > 0; off >>= 1)
        sum += __shfl_down(sum, off, 64);

    __shared__ float wsum[4];
    const int lane = threadIdx.x & 63;
    const int wid  = threadIdx.x >> 6;
    if (lane == 0) wsum[wid] = sum;
    __syncthreads();
    if (threadIdx.x == 0)
        partial[blockIdx.x] = wsum[0] + wsum[1] + wsum[2] + wsum[3];
}

__global__ __launch_bounds__(1024)
void lace_reduce_kernel(const float* __restrict__ partial,
                        float*       __restrict__ out)
{
    float s = 0.0f;
    for (int i = threadIdx.x; i < NBLK; i += 1024)
        s += partial[i];

    #pragma unroll
    for (int off = 32; off > 0; off >>= 1)
        s += __shfl_down(s, off, 64);

    __shared__ float wsum[16];
    const int lane = threadIdx.x & 63;
    const int wid  = threadIdx.x >> 6;
    if (lane == 0) wsum[wid] = s;
    __syncthreads();
    if (threadIdx.x == 0) {
        float total = 0.0f;
        #pragma unroll
        for (int i = 0; i < 16; ++i) total += wsum[i];
        out[0] = total * INV_N;
    }
}

extern "C" void kernel_launch(void* const* d_in, const int* in_sizes, int n_in,
                              void* d_out, int out_size, void* d_ws, size_t ws_size,
                              hipStream_t stream) {
    const float4* lg4 = (const float4*)d_in[0];
    const int4*   tg4 = (const int4*)d_in[1];
    float* out     = (float*)d_out;
    float* partial = (float*)d_ws;   // 2816 floats

    lace_partial_kernel<<<NBLK, 256, 0, stream>>>(lg4, tg4, partial);
    lace_reduce_kernel<<<1, 1024, 0, stream>>>(partial, out);
}